// Round 7
// baseline (241.968 us; speedup 1.0000x reference)
//
#include <hip/hip_runtime.h>

#define NTOT 131072   // B*T = 16*8192
#define KCB  512
#define DIM  64

__device__ __forceinline__ float wave_sum(float v) {
#pragma unroll
  for (int off = 32; off; off >>= 1) v += __shfl_xor(v, off, 64);
  return v;
}

// ---------------------------------------------------------------------------
// K1: distances + argmin + one-hot + idx + counts + dw scatter.
// 256 blocks x 512 threads (8 waves). Barrier-free main loop (R6-proven).
// ROUND 7 CHANGE (single variable): GEMM d-loop unroll 4 -> 2. The fully
// flattened GEMM was ~35KB of code; the 8-iteration tile loop re-streamed a
// ~40KB body through the 32KB I$ every tile => fetch-bound issue. Rolled,
// the body is ~6KB and resident.
// LDS: embt 128K + xls 16.3K + lcnt 2K = 146.3 KiB.
// ---------------------------------------------------------------------------
__global__ __launch_bounds__(512, 2) void k_dist(
    const float* __restrict__ x_g,      // [D][N]
    const float* __restrict__ emb_g,    // [K][D]
    float* __restrict__ dist_out,       // [N][K]
    float* __restrict__ enc_out,        // [N][K]
    int* __restrict__ idx_out,          // [N]
    unsigned* __restrict__ cnt_g,       // [K]
    float* __restrict__ dw_g)           // [K][D]
{
  __shared__ __align__(16) float embt[DIM][KCB];   // -2*emb[k][d] at [d][k]
  __shared__ __align__(16) float xls[8][8][65];    // per-wave 8 rows, padded
  __shared__ unsigned lcnt[KCB];

  const int t = threadIdx.x;
  const int lane = t & 63;
  const int w = t >> 6;

  lcnt[t] = 0u;

  // ---- stage embedding (once): thread t owns code row t
  {
    const float* er = emb_g + t * DIM;
#pragma unroll
    for (int d0 = 0; d0 < DIM; d0 += 4) {
      const float4 e = *reinterpret_cast<const float4*>(er + d0);
      embt[d0 + 0][t] = -2.f * e.x;
      embt[d0 + 1][t] = -2.f * e.y;
      embt[d0 + 2][t] = -2.f * e.z;
      embt[d0 + 3][t] = -2.f * e.w;
    }
  }
  __syncthreads();   // the only block-wide barrier (until the final one)

  // ---- per-lane |emb|^2 for its 8 k's: sq = 0.25 * sum((-2e)^2)
  float ebr[8] = {0.f, 0.f, 0.f, 0.f, 0.f, 0.f, 0.f, 0.f};
  for (int d = 0; d < DIM; ++d) {
    const float4 a = *reinterpret_cast<const float4*>(&embt[d][4 * lane]);
    const float4 b = *reinterpret_cast<const float4*>(&embt[d][256 + 4 * lane]);
    ebr[0] = fmaf(a.x, a.x, ebr[0]); ebr[1] = fmaf(a.y, a.y, ebr[1]);
    ebr[2] = fmaf(a.z, a.z, ebr[2]); ebr[3] = fmaf(a.w, a.w, ebr[3]);
    ebr[4] = fmaf(b.x, b.x, ebr[4]); ebr[5] = fmaf(b.y, b.y, ebr[5]);
    ebr[6] = fmaf(b.z, b.z, ebr[6]); ebr[7] = fmaf(b.w, b.w, ebr[7]);
  }
#pragma unroll
  for (int j = 0; j < 8; ++j) ebr[j] *= 0.25f;

  const int nb = blockIdx.x * 512;
  const int r_own = lane & 7;           // this lane's row within wave tile
  const int dgc   = lane >> 3;          // d-chunk 0..7

  for (int tt = 0; tt < 8; ++tt) {
    const int n0w = nb + tt * 64 + w * 8;   // wave's 8 rows

    // fence: prior iteration's xls reads retire before overwrite
    asm volatile("" ::: "memory");

    // ---- wave-private x load: lane loads row r_own, d-chunk dgc (8 vals)
    float xv[8];
#pragma unroll
    for (int j = 0; j < 8; ++j)
      xv[j] = x_g[(size_t)(dgc * 8 + j) * NTOT + n0w + r_own];
#pragma unroll
    for (int j = 0; j < 8; ++j)
      xls[w][r_own][dgc * 8 + j] = xv[j];

    // fence: staging writes ordered before reads (wave-synchronous LDS)
    asm volatile("" ::: "memory");

    // ---- |x|^2 for row r_own: partial over chunk, butterfly over chunks
    float ps = 0.f;
#pragma unroll
    for (int j = 0; j < 8; ++j) ps = fmaf(xv[j], xv[j], ps);
    ps += __shfl_xor(ps, 8, 64);
    ps += __shfl_xor(ps, 16, 64);
    ps += __shfl_xor(ps, 32, 64);       // lane r holds |x[row r]|^2 (r = lane&7)

    // ---- transpose via LDS: lane l holds x[row r][d=l]
    float xr[8];
#pragma unroll
    for (int r = 0; r < 8; ++r) xr[r] = xls[w][r][lane];

    // ---- accumulators init with |e_k|^2
    float acc[8][8];
#pragma unroll
    for (int r = 0; r < 8; ++r)
#pragma unroll
      for (int j = 0; j < 8; ++j) acc[r][j] = ebr[j];

    // ---- GEMM: acc[r][j] += x[r][d] * (-2 e[k_j][d])
    // unroll 2 (NOT 4/full): keeps the tile-loop body ~6KB, resident in I$.
#pragma unroll 2
    for (int d = 0; d < DIM; ++d) {
      const float4 e0 = *reinterpret_cast<const float4*>(&embt[d][4 * lane]);
      const float4 e1 = *reinterpret_cast<const float4*>(&embt[d][256 + 4 * lane]);
#pragma unroll
      for (int r = 0; r < 8; ++r) {
        const float s = __uint_as_float(
            __builtin_amdgcn_readlane(__float_as_uint(xr[r]), d));
        acc[r][0] = fmaf(s, e0.x, acc[r][0]);
        acc[r][1] = fmaf(s, e0.y, acc[r][1]);
        acc[r][2] = fmaf(s, e0.z, acc[r][2]);
        acc[r][3] = fmaf(s, e0.w, acc[r][3]);
        acc[r][4] = fmaf(s, e1.x, acc[r][4]);
        acc[r][5] = fmaf(s, e1.y, acc[r][5]);
        acc[r][6] = fmaf(s, e1.z, acc[r][6]);
        acc[r][7] = fmaf(s, e1.w, acc[r][7]);
      }
    }

    // ---- epilogue per row: +|x|^2, argmin, float4 stores, idx/cnt/dw
#pragma unroll
    for (int r = 0; r < 8; ++r) {
      const int nr = n0w + r;
      const float xs = __uint_as_float(
          __builtin_amdgcn_readlane(__float_as_uint(ps), r));
      float dv[8];
#pragma unroll
      for (int j = 0; j < 8; ++j) dv[j] = acc[r][j] + xs;

      // argmin, first-min tie-break: pack (dist_bits, k); dists > 0
      unsigned long long best = ~0ull;
#pragma unroll
      for (int j = 0; j < 8; ++j) {
        const unsigned kk = (j < 4) ? (unsigned)(4 * lane + j)
                                    : (unsigned)(256 + 4 * lane + (j - 4));
        const unsigned long long pk =
            ((unsigned long long)__float_as_uint(dv[j]) << 32) | kk;
        best = pk < best ? pk : best;
      }
#pragma unroll
      for (int off = 32; off; off >>= 1) {
        const unsigned long long o = __shfl_xor(best, off, 64);
        best = o < best ? o : best;
      }
      const int kmin = (int)(best & 0xFFFFFFFFull);

      // contiguous 1KB wave windows (regions are 8B-aligned; unaligned
      // dwordx4 is legal on gfx9+ global ops)
      float* dp = dist_out + (size_t)nr * KCB + 4 * lane;
      float4 q;
      q.x = dv[0]; q.y = dv[1]; q.z = dv[2]; q.w = dv[3];
      *reinterpret_cast<float4*>(dp) = q;
      q.x = dv[4]; q.y = dv[5]; q.z = dv[6]; q.w = dv[7];
      *reinterpret_cast<float4*>(dp + 256) = q;

      float* ep = enc_out + (size_t)nr * KCB + 4 * lane;
      const int k0 = 4 * lane;
      float4 z;
      z.x = (kmin == k0)     ? 1.f : 0.f;
      z.y = (kmin == k0 + 1) ? 1.f : 0.f;
      z.z = (kmin == k0 + 2) ? 1.f : 0.f;
      z.w = (kmin == k0 + 3) ? 1.f : 0.f;
      *reinterpret_cast<float4*>(ep) = z;
      z.x = (kmin == 256 + k0)     ? 1.f : 0.f;
      z.y = (kmin == 256 + k0 + 1) ? 1.f : 0.f;
      z.z = (kmin == 256 + k0 + 2) ? 1.f : 0.f;
      z.w = (kmin == 256 + k0 + 3) ? 1.f : 0.f;
      *reinterpret_cast<float4*>(ep + 256) = z;

      if (lane == 0) {
        idx_out[nr] = kmin;
        atomicAdd(&lcnt[kmin], 1u);
      }
      // dw[kmin][d] += x[nr][d], d = lane
      unsafeAtomicAdd(dw_g + ((size_t)kmin << 6) + lane, xr[r]);
    }
  }

  __syncthreads();
  if (lcnt[t]) atomicAdd(&cnt_g[t], lcnt[t]);
}

// ---------------------------------------------------------------------------
// K3: cluster EMA + laplace + new_emb + perplexity (1 block, 512 threads)
// ---------------------------------------------------------------------------
__global__ __launch_bounds__(512, 1) void k_final(
    const float* __restrict__ ema_w, const float* __restrict__ ema_cs,
    const unsigned* __restrict__ cnt, const float* __restrict__ dw,
    float* __restrict__ nemb, float* __restrict__ out)
{
  __shared__ float red[8];
  __shared__ float bc;
  const int t = threadIdx.x;
  const int lane = t & 63, w = t >> 6;

  const float c = (float)cnt[t];
  const float craw = ema_cs[t] * 0.99f + 0.01f * c;

  float s = wave_sum(craw);
  if (lane == 0) red[w] = s;
  __syncthreads();
  if (t == 0) {
    float a = 0.f;
#pragma unroll
    for (int i = 0; i < 8; ++i) a += red[i];
    bc = a;
  }
  __syncthreads();
  const float n = bc;
  const float clus = (craw + 1e-5f) / (n + 512.f * 1e-5f) * n;

  const float4* wr = reinterpret_cast<const float4*>(ema_w + t * 64);
  const float4* dr = reinterpret_cast<const float4*>(dw + t * 64);
  float4* nr = reinterpret_cast<float4*>(nemb + t * 64);
#pragma unroll
  for (int q = 0; q < 16; ++q) {
    const float4 wv = wr[q], dv = dr[q];
    float4 o;
    o.x = (wv.x * 0.99f + 0.01f * dv.x) / clus;
    o.y = (wv.y * 0.99f + 0.01f * dv.y) / clus;
    o.z = (wv.z * 0.99f + 0.01f * dv.z) / clus;
    o.w = (wv.w * 0.99f + 0.01f * dv.w) / clus;
    nr[q] = o;
  }

  const float p = c * (1.f / 131072.f);
  const float term = p * logf(p + 1e-10f);
  float s2 = wave_sum(term);
  if (lane == 0) red[w] = s2;
  __syncthreads();
  if (t == 0) {
    float a = 0.f;
#pragma unroll
    for (int i = 0; i < 8; ++i) a += red[i];
    out[8388609] = expf(-a);   // perplexity slot
  }
}

// ---------------------------------------------------------------------------
// K4: quantized gather + transposed write + commitment loss
// ---------------------------------------------------------------------------
__global__ __launch_bounds__(256, 4) void k_quant(
    const float* __restrict__ x_g, const int* __restrict__ idx_g,
    const float* __restrict__ nemb, float* __restrict__ out)
{
  float lsum = 0.f;
  const int stride = gridDim.x * 256;
  for (int i = blockIdx.x * 256 + threadIdx.x; i < (DIM * NTOT / 4); i += stride) {
    const int d = i >> 15;                 // / (NTOT/4)
    const int n4 = i & ((NTOT / 4) - 1);
    const float4 xv = *reinterpret_cast<const float4*>(x_g + ((size_t)d << 17) + 4 * n4);
    const int4 id = *reinterpret_cast<const int4*>(idx_g + 4 * n4);
    const float q0 = nemb[(id.x << 6) + d];
    const float q1 = nemb[(id.y << 6) + d];
    const float q2 = nemb[(id.z << 6) + d];
    const float q3 = nemb[(id.w << 6) + d];
    const float e0 = q0 - xv.x, e1 = q1 - xv.y, e2 = q2 - xv.z, e3 = q3 - xv.w;
    float* op = out + 1 + ((size_t)d << 17) + 4 * n4;   // quantized_st region
    op[0] = xv.x + e0;  // mimic x + (q - x) exactly
    op[1] = xv.y + e1;
    op[2] = xv.z + e2;
    op[3] = xv.w + e3;
    lsum += e0 * e0 + e1 * e1 + e2 * e2 + e3 * e3;
  }
  lsum = wave_sum(lsum);
  __shared__ float wsum[4];
  const int lane = threadIdx.x & 63, w = threadIdx.x >> 6;
  if (lane == 0) wsum[w] = lsum;
  __syncthreads();
  if (threadIdx.x == 0)
    unsafeAtomicAdd(out, (wsum[0] + wsum[1] + wsum[2] + wsum[3]) * (0.25f / 8388608.f));
}

// ---------------------------------------------------------------------------
extern "C" void kernel_launch(void* const* d_in, const int* in_sizes, int n_in,
                              void* d_out, int out_size, void* d_ws, size_t ws_size,
                              hipStream_t stream) {
  const float* x      = (const float*)d_in[0];   // [64][16][8192]
  const float* emb    = (const float*)d_in[1];   // [512][64]
  const float* ema_w  = (const float*)d_in[2];   // [512][64]
  const float* ema_cs = (const float*)d_in[3];   // [512]
  float* out = (float*)d_out;

  // d_out layout: loss@0 | q@1 (8388608) | perp@8388609 | enc@8388610 | dist@75497474
  float* enc_out  = out + 8388610;
  float* dist_out = out + 75497474;

  // ws layout: dw [512*64]f @0 | counts [512]u @131072 | new_emb @133120 | idx @264192
  char* ws = (char*)d_ws;
  float*    dw   = (float*)ws;
  unsigned* cnt  = (unsigned*)(ws + 131072);
  float*    nemb = (float*)(ws + 133120);
  int*      idx  = (int*)(ws + 264192);

  hipMemsetAsync(d_ws, 0, 133120, stream);          // zero dw + counts
  hipMemsetAsync(d_out, 0, sizeof(float), stream);  // zero loss accumulator

  k_dist<<<256, 512, 0, stream>>>(x, emb, dist_out, enc_out, idx, cnt, dw);
  k_final<<<1, 512, 0, stream>>>(ema_w, ema_cs, cnt, dw, nemb, out);
  k_quant<<<2048, 256, 0, stream>>>(x, idx, nemb, out);
}

// Round 8
// 240.687 us; speedup vs baseline: 1.0053x; 1.0053x over previous
//
#include <hip/hip_runtime.h>

#define NTOT 131072   // B*T = 16*8192
#define KCB  512
#define DIM  64

__device__ __forceinline__ float wave_sum(float v) {
#pragma unroll
  for (int off = 32; off; off >>= 1) v += __shfl_xor(v, off, 64);
  return v;
}

// ---------------------------------------------------------------------------
// K1: distances + argmin + one-hot + idx + counts + dw scatter.
// 256 blocks x 512 threads (8 waves). Barrier-free main loop (R6-proven).
// ROUND 8 CHANGE (single variable): software-pipelined x loads. Next tile's
// global loads are ISSUED BEFORE this tile's epilogue stores, so the loop-top
// s_waitcnt for the loads leaves the younger stores outstanding (vmcnt(~40))
// instead of draining ~32KB of stores+atomics through L2/HBM every tile
// (the hidden serialization that R6's loop-top fence was pinning in place).
// LDS: embt 128K + xls 16.3K + lcnt 2K = 146.3 KiB.
// ---------------------------------------------------------------------------
__global__ __launch_bounds__(512, 2) void k_dist(
    const float* __restrict__ x_g,      // [D][N]
    const float* __restrict__ emb_g,    // [K][D]
    float* __restrict__ dist_out,       // [N][K]
    float* __restrict__ enc_out,        // [N][K]
    int* __restrict__ idx_out,          // [N]
    unsigned* __restrict__ cnt_g,       // [K]
    float* __restrict__ dw_g)           // [K][D]
{
  __shared__ __align__(16) float embt[DIM][KCB];   // -2*emb[k][d] at [d][k]
  __shared__ __align__(16) float xls[8][8][65];    // per-wave 8 rows, padded
  __shared__ unsigned lcnt[KCB];

  const int t = threadIdx.x;
  const int lane = t & 63;
  const int w = t >> 6;

  lcnt[t] = 0u;

  // ---- stage embedding (once): thread t owns code row t
  {
    const float* er = emb_g + t * DIM;
#pragma unroll
    for (int d0 = 0; d0 < DIM; d0 += 4) {
      const float4 e = *reinterpret_cast<const float4*>(er + d0);
      embt[d0 + 0][t] = -2.f * e.x;
      embt[d0 + 1][t] = -2.f * e.y;
      embt[d0 + 2][t] = -2.f * e.z;
      embt[d0 + 3][t] = -2.f * e.w;
    }
  }
  __syncthreads();   // the only block-wide barrier (until the final one)

  // ---- per-lane |emb|^2 for its 8 k's: sq = 0.25 * sum((-2e)^2)
  float ebr[8] = {0.f, 0.f, 0.f, 0.f, 0.f, 0.f, 0.f, 0.f};
  for (int d = 0; d < DIM; ++d) {
    const float4 a = *reinterpret_cast<const float4*>(&embt[d][4 * lane]);
    const float4 b = *reinterpret_cast<const float4*>(&embt[d][256 + 4 * lane]);
    ebr[0] = fmaf(a.x, a.x, ebr[0]); ebr[1] = fmaf(a.y, a.y, ebr[1]);
    ebr[2] = fmaf(a.z, a.z, ebr[2]); ebr[3] = fmaf(a.w, a.w, ebr[3]);
    ebr[4] = fmaf(b.x, b.x, ebr[4]); ebr[5] = fmaf(b.y, b.y, ebr[5]);
    ebr[6] = fmaf(b.z, b.z, ebr[6]); ebr[7] = fmaf(b.w, b.w, ebr[7]);
  }
#pragma unroll
  for (int j = 0; j < 8; ++j) ebr[j] *= 0.25f;

  const int nb = blockIdx.x * 512;
  const int r_own = lane & 7;           // this lane's row within wave tile
  const int dgc   = lane >> 3;          // d-chunk 0..7

  // ---- prologue: issue tile 0's x loads
  float xv[8];
  {
    const int n0w = nb + w * 8;
#pragma unroll
    for (int j = 0; j < 8; ++j)
      xv[j] = x_g[(size_t)(dgc * 8 + j) * NTOT + n0w + r_own];
  }

  for (int tt = 0; tt < 8; ++tt) {
    const int n0w = nb + tt * 64 + w * 8;   // wave's 8 rows

    // fence: prior iteration's xls reads retire before overwrite; also keeps
    // the prefetched loads from sinking below this point
    asm volatile("" ::: "memory");

    // ---- stage prefetched x into wave-private LDS (waits on loads only;
    // younger epilogue stores from last tile stay outstanding)
#pragma unroll
    for (int j = 0; j < 8; ++j)
      xls[w][r_own][dgc * 8 + j] = xv[j];

    // fence: staging writes ordered before reads (wave-synchronous LDS)
    asm volatile("" ::: "memory");

    // ---- |x|^2 for row r_own: partial over chunk, butterfly over chunks
    float ps = 0.f;
#pragma unroll
    for (int j = 0; j < 8; ++j) ps = fmaf(xv[j], xv[j], ps);
    ps += __shfl_xor(ps, 8, 64);
    ps += __shfl_xor(ps, 16, 64);
    ps += __shfl_xor(ps, 32, 64);       // lane r holds |x[row r]|^2 (r = lane&7)

    // ---- transpose via LDS: lane l holds x[row r][d=l]
    float xr[8];
#pragma unroll
    for (int r = 0; r < 8; ++r) xr[r] = xls[w][r][lane];

    // ---- accumulators init with |e_k|^2
    float acc[8][8];
#pragma unroll
    for (int r = 0; r < 8; ++r)
#pragma unroll
      for (int j = 0; j < 8; ++j) acc[r][j] = ebr[j];

    // ---- GEMM: acc[r][j] += x[r][d] * (-2 e[k_j][d])
#pragma unroll 2
    for (int d = 0; d < DIM; ++d) {
      const float4 e0 = *reinterpret_cast<const float4*>(&embt[d][4 * lane]);
      const float4 e1 = *reinterpret_cast<const float4*>(&embt[d][256 + 4 * lane]);
#pragma unroll
      for (int r = 0; r < 8; ++r) {
        const float s = __uint_as_float(
            __builtin_amdgcn_readlane(__float_as_uint(xr[r]), d));
        acc[r][0] = fmaf(s, e0.x, acc[r][0]);
        acc[r][1] = fmaf(s, e0.y, acc[r][1]);
        acc[r][2] = fmaf(s, e0.z, acc[r][2]);
        acc[r][3] = fmaf(s, e0.w, acc[r][3]);
        acc[r][4] = fmaf(s, e1.x, acc[r][4]);
        acc[r][5] = fmaf(s, e1.y, acc[r][5]);
        acc[r][6] = fmaf(s, e1.z, acc[r][6]);
        acc[r][7] = fmaf(s, e1.w, acc[r][7]);
      }
    }

    // ---- prefetch NEXT tile's x BEFORE the epilogue stores (pipeline)
    if (tt < 7) {
      const int n1w = nb + (tt + 1) * 64 + w * 8;
#pragma unroll
      for (int j = 0; j < 8; ++j)
        xv[j] = x_g[(size_t)(dgc * 8 + j) * NTOT + n1w + r_own];
    }
    // fence: pin load-issue BEFORE the epilogue's stores/atomics so the
    // loop-top waitcnt for xv never has to drain them
    asm volatile("" ::: "memory");

    // ---- epilogue per row: +|x|^2, argmin, float4 stores, idx/cnt/dw
#pragma unroll
    for (int r = 0; r < 8; ++r) {
      const int nr = n0w + r;
      const float xs = __uint_as_float(
          __builtin_amdgcn_readlane(__float_as_uint(ps), r));
      float dv[8];
#pragma unroll
      for (int j = 0; j < 8; ++j) dv[j] = acc[r][j] + xs;

      // argmin, first-min tie-break: pack (dist_bits, k); dists > 0
      unsigned long long best = ~0ull;
#pragma unroll
      for (int j = 0; j < 8; ++j) {
        const unsigned kk = (j < 4) ? (unsigned)(4 * lane + j)
                                    : (unsigned)(256 + 4 * lane + (j - 4));
        const unsigned long long pk =
            ((unsigned long long)__float_as_uint(dv[j]) << 32) | kk;
        best = pk < best ? pk : best;
      }
#pragma unroll
      for (int off = 32; off; off >>= 1) {
        const unsigned long long o = __shfl_xor(best, off, 64);
        best = o < best ? o : best;
      }
      const int kmin = (int)(best & 0xFFFFFFFFull);

      // contiguous 1KB wave windows (regions are 8B-aligned; unaligned
      // dwordx4 is legal on gfx9+ global ops)
      float* dp = dist_out + (size_t)nr * KCB + 4 * lane;
      float4 q;
      q.x = dv[0]; q.y = dv[1]; q.z = dv[2]; q.w = dv[3];
      *reinterpret_cast<float4*>(dp) = q;
      q.x = dv[4]; q.y = dv[5]; q.z = dv[6]; q.w = dv[7];
      *reinterpret_cast<float4*>(dp + 256) = q;

      float* ep = enc_out + (size_t)nr * KCB + 4 * lane;
      const int k0 = 4 * lane;
      float4 z;
      z.x = (kmin == k0)     ? 1.f : 0.f;
      z.y = (kmin == k0 + 1) ? 1.f : 0.f;
      z.z = (kmin == k0 + 2) ? 1.f : 0.f;
      z.w = (kmin == k0 + 3) ? 1.f : 0.f;
      *reinterpret_cast<float4*>(ep) = z;
      z.x = (kmin == 256 + k0)     ? 1.f : 0.f;
      z.y = (kmin == 256 + k0 + 1) ? 1.f : 0.f;
      z.z = (kmin == 256 + k0 + 2) ? 1.f : 0.f;
      z.w = (kmin == 256 + k0 + 3) ? 1.f : 0.f;
      *reinterpret_cast<float4*>(ep + 256) = z;

      if (lane == 0) {
        idx_out[nr] = kmin;
        atomicAdd(&lcnt[kmin], 1u);
      }
      // dw[kmin][d] += x[nr][d], d = lane
      unsafeAtomicAdd(dw_g + ((size_t)kmin << 6) + lane, xr[r]);
    }
  }

  __syncthreads();
  if (lcnt[t]) atomicAdd(&cnt_g[t], lcnt[t]);
}

// ---------------------------------------------------------------------------
// K3: cluster EMA + laplace + new_emb + perplexity (1 block, 512 threads)
// ---------------------------------------------------------------------------
__global__ __launch_bounds__(512, 1) void k_final(
    const float* __restrict__ ema_w, const float* __restrict__ ema_cs,
    const unsigned* __restrict__ cnt, const float* __restrict__ dw,
    float* __restrict__ nemb, float* __restrict__ out)
{
  __shared__ float red[8];
  __shared__ float bc;
  const int t = threadIdx.x;
  const int lane = t & 63, w = t >> 6;

  const float c = (float)cnt[t];
  const float craw = ema_cs[t] * 0.99f + 0.01f * c;

  float s = wave_sum(craw);
  if (lane == 0) red[w] = s;
  __syncthreads();
  if (t == 0) {
    float a = 0.f;
#pragma unroll
    for (int i = 0; i < 8; ++i) a += red[i];
    bc = a;
  }
  __syncthreads();
  const float n = bc;
  const float clus = (craw + 1e-5f) / (n + 512.f * 1e-5f) * n;

  const float4* wr = reinterpret_cast<const float4*>(ema_w + t * 64);
  const float4* dr = reinterpret_cast<const float4*>(dw + t * 64);
  float4* nr = reinterpret_cast<float4*>(nemb + t * 64);
#pragma unroll
  for (int q = 0; q < 16; ++q) {
    const float4 wv = wr[q], dv = dr[q];
    float4 o;
    o.x = (wv.x * 0.99f + 0.01f * dv.x) / clus;
    o.y = (wv.y * 0.99f + 0.01f * dv.y) / clus;
    o.z = (wv.z * 0.99f + 0.01f * dv.z) / clus;
    o.w = (wv.w * 0.99f + 0.01f * dv.w) / clus;
    nr[q] = o;
  }

  const float p = c * (1.f / 131072.f);
  const float term = p * logf(p + 1e-10f);
  float s2 = wave_sum(term);
  if (lane == 0) red[w] = s2;
  __syncthreads();
  if (t == 0) {
    float a = 0.f;
#pragma unroll
    for (int i = 0; i < 8; ++i) a += red[i];
    out[8388609] = expf(-a);   // perplexity slot
  }
}

// ---------------------------------------------------------------------------
// K4: quantized gather + transposed write + commitment loss
// ---------------------------------------------------------------------------
__global__ __launch_bounds__(256, 4) void k_quant(
    const float* __restrict__ x_g, const int* __restrict__ idx_g,
    const float* __restrict__ nemb, float* __restrict__ out)
{
  float lsum = 0.f;
  const int stride = gridDim.x * 256;
  for (int i = blockIdx.x * 256 + threadIdx.x; i < (DIM * NTOT / 4); i += stride) {
    const int d = i >> 15;                 // / (NTOT/4)
    const int n4 = i & ((NTOT / 4) - 1);
    const float4 xv = *reinterpret_cast<const float4*>(x_g + ((size_t)d << 17) + 4 * n4);
    const int4 id = *reinterpret_cast<const int4*>(idx_g + 4 * n4);
    const float q0 = nemb[(id.x << 6) + d];
    const float q1 = nemb[(id.y << 6) + d];
    const float q2 = nemb[(id.z << 6) + d];
    const float q3 = nemb[(id.w << 6) + d];
    const float e0 = q0 - xv.x, e1 = q1 - xv.y, e2 = q2 - xv.z, e3 = q3 - xv.w;
    float* op = out + 1 + ((size_t)d << 17) + 4 * n4;   // quantized_st region
    op[0] = xv.x + e0;  // mimic x + (q - x) exactly
    op[1] = xv.y + e1;
    op[2] = xv.z + e2;
    op[3] = xv.w + e3;
    lsum += e0 * e0 + e1 * e1 + e2 * e2 + e3 * e3;
  }
  lsum = wave_sum(lsum);
  __shared__ float wsum[4];
  const int lane = threadIdx.x & 63, w = threadIdx.x >> 6;
  if (lane == 0) wsum[w] = lsum;
  __syncthreads();
  if (threadIdx.x == 0)
    unsafeAtomicAdd(out, (wsum[0] + wsum[1] + wsum[2] + wsum[3]) * (0.25f / 8388608.f));
}

// ---------------------------------------------------------------------------
extern "C" void kernel_launch(void* const* d_in, const int* in_sizes, int n_in,
                              void* d_out, int out_size, void* d_ws, size_t ws_size,
                              hipStream_t stream) {
  const float* x      = (const float*)d_in[0];   // [64][16][8192]
  const float* emb    = (const float*)d_in[1];   // [512][64]
  const float* ema_w  = (const float*)d_in[2];   // [512][64]
  const float* ema_cs = (const float*)d_in[3];   // [512]
  float* out = (float*)d_out;

  // d_out layout: loss@0 | q@1 (8388608) | perp@8388609 | enc@8388610 | dist@75497474
  float* enc_out  = out + 8388610;
  float* dist_out = out + 75497474;

  // ws layout: dw [512*64]f @0 | counts [512]u @131072 | new_emb @133120 | idx @264192
  char* ws = (char*)d_ws;
  float*    dw   = (float*)ws;
  unsigned* cnt  = (unsigned*)(ws + 131072);
  float*    nemb = (float*)(ws + 133120);
  int*      idx  = (int*)(ws + 264192);

  hipMemsetAsync(d_ws, 0, 133120, stream);          // zero dw + counts
  hipMemsetAsync(d_out, 0, sizeof(float), stream);  // zero loss accumulator

  k_dist<<<256, 512, 0, stream>>>(x, emb, dist_out, enc_out, idx, cnt, dw);
  k_final<<<1, 512, 0, stream>>>(ema_w, ema_cs, cnt, dw, nemb, out);
  k_quant<<<2048, 256, 0, stream>>>(x, idx, nemb, out);
}